// Round 10
// baseline (392.084 us; speedup 1.0000x reference)
//
#include <hip/hip_runtime.h>
#include <hip/hip_bf16.h>

#define DEVI static __device__ __forceinline__

typedef __attribute__((ext_vector_type(8))) short short8;
typedef __attribute__((ext_vector_type(4))) float f32x4;

#define B_   8
#define O_   100
#define N_   4096
#define TOKD 2048
#define D_   256
#define K_   128
#define H_   8
#define M_   (B_*N_)   // 32768

DEVI unsigned short f2bf(float f) {
    unsigned u = __float_as_uint(f);
    u = (u + 0x7FFFu + ((u >> 16) & 1u)) >> 16;   // RNE
    return (unsigned short)u;
}
DEVI float bf2f(unsigned v) { return __uint_as_float(v << 16); }

DEVI unsigned pkbf(float lo, float hi) {   // packed RNE f32->bf16 pair
    unsigned r;
    asm("v_cvt_pk_bf16_f32 %0, %1, %2" : "=v"(r) : "v"(lo), "v"(hi));
    return r;
}
DEVI short8 pack8(float4 x, float4 y) {
    union { unsigned u[4]; short8 s; } r;
    r.u[0] = pkbf(x.x, x.y); r.u[1] = pkbf(x.z, x.w);
    r.u[2] = pkbf(y.x, y.y); r.u[3] = pkbf(y.z, y.w);
    return r.s;
}

// ---------- merged: topk (blocks 0..799) + W_tok->bf16^T (800..2847) + q-fold (2848..2855) ----------
__global__ __launch_bounds__(256) void k_pre(const float* __restrict__ act,
                                             int* __restrict__ oidx,
                                             float* __restrict__ asum,
                                             const float* __restrict__ W,
                                             unsigned short* __restrict__ wtb,
                                             const float* __restrict__ pq,
                                             const float* __restrict__ Wq,
                                             const float* __restrict__ bqv,
                                             const float* __restrict__ Wk,
                                             const float* __restrict__ bkv,
                                             float* __restrict__ qW,
                                             float* __restrict__ qb) {
    __shared__ __align__(16) char smem[50304];
    const int t = threadIdx.x, lane = t & 63, wid = t >> 6;

    if (blockIdx.x >= 800) {
        const int bx = blockIdx.x - 800;
        if (bx < 2048) {                       // W_tok transpose+cast
            int idx = bx * 256 + t;
            int k = idx >> 8, n = idx & 255;
            wtb[n * TOKD + k] = f2bf(W[idx]);
            return;
        }
        // q-fold: qW[h][e] = qh[h]·Wk[e][h*32..], qb[h]
        float (*qpart)[32] = (float(*)[32])smem;
        float* qhl = (float*)(smem + 1024);
        const int h = bx - 2048;
        const int col = h * 32 + (t & 31), sl = t >> 5;
        float s = 0.f;
        #pragma unroll
        for (int e = 0; e < 32; ++e) s += pq[sl * 32 + e] * Wq[(sl * 32 + e) * D_ + col];
        qpart[sl][t & 31] = s;
        __syncthreads();
        if (t < 32) {
            float u = bqv[h * 32 + t];
            #pragma unroll
            for (int s8 = 0; s8 < 8; ++s8) u += qpart[s8][t];
            qhl[t] = u;
        }
        __syncthreads();
        float u = 0.f;
        #pragma unroll
        for (int dd = 0; dd < 32; ++dd) u += qhl[dd] * Wk[t * D_ + h * 32 + dd];
        qW[h * D_ + t] = u;
        if (t == 0) {
            float z = 0.f;
            for (int dd = 0; dd < 32; ++dd) z += qhl[dd] * bkv[h * 32 + dd];
            qb[h] = z;
        }
        return;
    }

    // ---- top-128 via value histogram (act uniform [0,1); exact jax tie-break at boundary)
    int* hist = (int*)smem;                               // 4096 bins
    unsigned long long* cand = (unsigned long long*)(smem + 16384);   // up to 4096
    int* csum = (int*)(smem + 49152);                     // 256 + 4 wave totals
    int* sb   = (int*)(smem + 50192);
    int* cnts = (int*)(smem + 50200);
    float* redf = (float*)(smem + 50208);
    unsigned long long* redu = (unsigned long long*)(smem + 50224);

    const int blk = blockIdx.x;
    const float* rp = act + (size_t)blk * N_;
    float fv[16]; unsigned vb[16]; int bins[16];
    float fs = 0.f;
    #pragma unroll
    for (int i = 0; i < 16; ++i) {
        float f = rp[t + i * 256];
        fv[i] = f; vb[i] = __float_as_uint(f);   // non-negative: bits order-preserving
        fs += f;
    }
    #pragma unroll
    for (int i = 0; i < 16; ++i) hist[t + i * 256] = 0;
    if (t == 0) { cnts[0] = 0; cnts[1] = 0; }
    #pragma unroll
    for (int m = 1; m < 64; m <<= 1) fs += __shfl_xor(fs, m);
    if (!lane) redf[wid] = fs;
    __syncthreads();
    if (t == 0) asum[blk] = fmaxf(redf[0] + redf[1] + redf[2] + redf[3], 1e-8f);

    #pragma unroll
    for (int i = 0; i < 16; ++i) {             // monotone binning (floor), clamped
        float f = fv[i];
        int b = (f >= 1.0f) ? 4095 : ((f > 0.f) ? (int)(f * 4096.f) : 0);
        bins[i] = b;
        atomicAdd(&hist[b], 1);
    }
    __syncthreads();

    int cs = 0;                                 // chunk sum: bins [16t,16t+16)
    #pragma unroll
    for (int i = 0; i < 16; ++i) cs += hist[t * 16 + i];
    int v = cs;
    #pragma unroll
    for (int off = 1; off < 64; off <<= 1) {
        int o = __shfl_down(v, off);
        if (lane + off < 64) v += o;
    }
    if (!lane) csum[256 + wid] = v;
    __syncthreads();
    int stot = 0;
    for (int w2 = wid + 1; w2 < 4; ++w2) stot += csum[256 + w2];
    int suff = v + stot;
    csum[t] = suff;
    __syncthreads();
    int nxtc = (t < 255) ? csum[t + 1] : 0;
    if (suff >= K_ && nxtc < K_) {
        int run = nxtc, bstar = t * 16;
        for (int bi = 15; bi >= 0; --bi) {
            run += hist[t * 16 + bi];
            if (run >= K_) { bstar = t * 16 + bi; break; }
        }
        sb[0] = bstar;
    }
    __syncthreads();
    const int bstar = sb[0];

    #pragma unroll
    for (int i = 0; i < 16; ++i) {
        if (bins[i] > bstar) {
            int p = atomicAdd(&cnts[0], 1);
            oidx[blk * K_ + p] = t + i * 256;
        } else if (bins[i] == bstar) {
            int p = atomicAdd(&cnts[1], 1);
            cand[p] = ((unsigned long long)vb[i] << 16) | (unsigned)(4095 - (t + i * 256));
        }
    }
    __syncthreads();
    const int g = cnts[0], E = cnts[1], m = K_ - g;
    unsigned long long last = ~0ull;
    for (int slot = 0; slot < m; ++slot) {
        unsigned long long best = 0;
        for (int i = t; i < E; i += 256) {
            unsigned long long e = cand[i];
            if (e < last && e > best) best = e;
        }
        #pragma unroll
        for (int mm = 1; mm < 64; mm <<= 1) {
            unsigned long long o = __shfl_xor(best, mm);
            if (o > best) best = o;
        }
        if (!lane) redu[wid] = best;
        __syncthreads();
        best = redu[0];
        if (redu[1] > best) best = redu[1];
        if (redu[2] > best) best = redu[2];
        if (redu[3] > best) best = redu[3];
        if (t == 0) oidx[blk * K_ + g + slot] = 4095 - (int)(best & 0xFFFFull);
        last = best;
        __syncthreads();
    }
}

// ---------- GEMM1 + bias + LN fused: DIRECT-TO-VGPR, zero LDS / zero barriers in main loop ----------
// 64x256 tile, 8 waves (2x4), wave tile 32x64. A f32->reg->cvt (1-iter cover);
// B bf16 dwordx4 direct, reg double-buffer (2-iter cover). All waits compiler-counted vmcnt.
#define GBODY(KT, BCUR)                                                                          \
    {                                                                                            \
        _Pragma("unroll")                                                                        \
        for (int mi = 0; mi < 2; ++mi)                                                           \
            _Pragma("unroll")                                                                    \
            for (int ni = 0; ni < 4; ++ni) {                                                     \
                acc[mi][ni] = __builtin_amdgcn_mfma_f32_16x16x32_bf16(ab[mi*2+0], BCUR[ni*2+0], acc[mi][ni], 0, 0, 0); \
                acc[mi][ni] = __builtin_amdgcn_mfma_f32_16x16x32_bf16(ab[mi*2+1], BCUR[ni*2+1], acc[mi][ni], 0, 0, 0); \
            }                                                                                    \
        ab[0] = pack8(t00, t01); ab[1] = pack8(t02, t03);                                        \
        ab[2] = pack8(t10, t11); ab[3] = pack8(t12, t13);                                        \
        if ((KT) + 2 < NT) {                                                                     \
            const float* ap0 = a0p + ((KT) + 2) * 64;                                            \
            const float* ap1 = a1p + ((KT) + 2) * 64;                                            \
            t00 = *(const float4*)(ap0);      t01 = *(const float4*)(ap0 + 4);                   \
            t02 = *(const float4*)(ap0 + 32); t03 = *(const float4*)(ap0 + 36);                  \
            t10 = *(const float4*)(ap1);      t11 = *(const float4*)(ap1 + 4);                   \
            t12 = *(const float4*)(ap1 + 32); t13 = *(const float4*)(ap1 + 36);                  \
            const unsigned short* q0 = b0p + ((KT) + 2) * 64;                                    \
            const unsigned short* q1 = b1p + ((KT) + 2) * 64;                                    \
            const unsigned short* q2 = b2p + ((KT) + 2) * 64;                                    \
            const unsigned short* q3 = b3p + ((KT) + 2) * 64;                                    \
            BCUR[0] = *(const short8*)(q0); BCUR[1] = *(const short8*)(q0 + 32);                 \
            BCUR[2] = *(const short8*)(q1); BCUR[3] = *(const short8*)(q1 + 32);                 \
            BCUR[4] = *(const short8*)(q2); BCUR[5] = *(const short8*)(q2 + 32);                 \
            BCUR[6] = *(const short8*)(q3); BCUR[7] = *(const short8*)(q3 + 32);                 \
        }                                                                                        \
    }

__global__ __launch_bounds__(512) void k_gemm1(const float* __restrict__ A,
                                               const unsigned short* __restrict__ Bt,
                                               const float* __restrict__ btok,
                                               const float* __restrict__ g,
                                               const float* __restrict__ bt,
                                               unsigned short* __restrict__ tp) {
    __shared__ __align__(16) float ep[32 * 260];    // epilogue only (33.3 KB)
    const int t = threadIdx.x;
    const int bm = blockIdx.x;
    const int lane = t & 63, w = t >> 6;
    const int wm = w >> 2, wn = w & 3;       // 2x4 waves, wave tile 32x64
    const int lr = lane >> 4, lc = lane & 15;
    const int NT = TOKD / 64;                // 32

    const float* a0p = A + (size_t)(bm * 64 + wm * 32 + lc) * TOKD + lr * 8;
    const float* a1p = a0p + (size_t)16 * TOKD;
    const unsigned short* b0p = Bt + (size_t)(wn * 64 + lc) * TOKD + lr * 8;
    const unsigned short* b1p = b0p + (size_t)16 * TOKD;
    const unsigned short* b2p = b0p + (size_t)32 * TOKD;
    const unsigned short* b3p = b0p + (size_t)48 * TOKD;

    f32x4 acc[2][4] = {};
    short8 bS0[8], bS1[8];                   // B reg dbuf [ni*2+kk]
    short8 ab[4];                            // current A bf16 [mi*2+kk]
    float4 t00, t01, t02, t03, t10, t11, t12, t13;   // A f32 staging (next tile)

    // ---- prologue: A(0)->temps->cvt, B(0)->bS0, B(1)->bS1, A(1)->temps
    t00 = *(const float4*)(a0p);      t01 = *(const float4*)(a0p + 4);
    t02 = *(const float4*)(a0p + 32); t03 = *(const float4*)(a0p + 36);
    t10 = *(const float4*)(a1p);      t11 = *(const float4*)(a1p + 4);
    t12 = *(const float4*)(a1p + 32); t13 = *(const float4*)(a1p + 36);
    bS0[0] = *(const short8*)(b0p);      bS0[1] = *(const short8*)(b0p + 32);
    bS0[2] = *(const short8*)(b1p);      bS0[3] = *(const short8*)(b1p + 32);
    bS0[4] = *(const short8*)(b2p);      bS0[5] = *(const short8*)(b2p + 32);
    bS0[6] = *(const short8*)(b3p);      bS0[7] = *(const short8*)(b3p + 32);
    bS1[0] = *(const short8*)(b0p + 64); bS1[1] = *(const short8*)(b0p + 96);
    bS1[2] = *(const short8*)(b1p + 64); bS1[3] = *(const short8*)(b1p + 96);
    bS1[4] = *(const short8*)(b2p + 64); bS1[5] = *(const short8*)(b2p + 96);
    bS1[6] = *(const short8*)(b3p + 64); bS1[7] = *(const short8*)(b3p + 96);
    ab[0] = pack8(t00, t01); ab[1] = pack8(t02, t03);
    ab[2] = pack8(t10, t11); ab[3] = pack8(t12, t13);
    t00 = *(const float4*)(a0p + 64);  t01 = *(const float4*)(a0p + 68);
    t02 = *(const float4*)(a0p + 96);  t03 = *(const float4*)(a0p + 100);
    t10 = *(const float4*)(a1p + 64);  t11 = *(const float4*)(a1p + 68);
    t12 = *(const float4*)(a1p + 96);  t13 = *(const float4*)(a1p + 100);

    for (int kt = 0; kt < NT; kt += 2) {
        GBODY(kt, bS0)
        GBODY(kt + 1, bS1)
    }

    // ---- fused epilogue: bias + LN + bf16 store, 2 chunks of 32 rows
    const int col0 = lane * 4;
    float4 b4 = *(const float4*)(btok + col0);
    float4 g4 = *(const float4*)(g + col0);
    float4 t4 = *(const float4*)(bt + col0);
    __syncthreads();
    #pragma unroll
    for (int c = 0; c < 2; ++c) {
        if (wm == c) {
            #pragma unroll
            for (int mi = 0; mi < 2; ++mi)
                #pragma unroll
                for (int ni = 0; ni < 4; ++ni)
                    #pragma unroll
                    for (int r = 0; r < 4; ++r)
                        ep[(mi * 16 + lr * 4 + r) * 260 + wn * 64 + ni * 16 + lc] = acc[mi][ni][r];
        }
        __syncthreads();
        #pragma unroll
        for (int rr = 0; rr < 4; ++rr) {
            int row = w * 4 + rr;
            float4 x4 = *(const float4*)(ep + row * 260 + col0);
            float x0 = x4.x + b4.x, x1 = x4.y + b4.y, x2 = x4.z + b4.z, x3 = x4.w + b4.w;
            float s = x0 + x1 + x2 + x3;
            float q = x0*x0 + x1*x1 + x2*x2 + x3*x3;
            #pragma unroll
            for (int m = 1; m < 64; m <<= 1) { s += __shfl_xor(s, m); q += __shfl_xor(q, m); }
            float mean = s * (1.f/256.f);
            float var = q * (1.f/256.f) - mean * mean;
            float rs = rsqrtf(var + 1e-5f);
            ushort4 o;
            o.x = f2bf((x0-mean)*rs*g4.x + t4.x);
            o.y = f2bf((x1-mean)*rs*g4.y + t4.y);
            o.z = f2bf((x2-mean)*rs*g4.z + t4.z);
            o.w = f2bf((x3-mean)*rs*g4.w + t4.w);
            *(ushort4*)(tp + (size_t)(bm * 64 + c * 32 + row) * D_ + col0) = o;
        }
        __syncthreads();
    }
}

// ---------- weighted-average partials (grid z-split x5 for occupancy) ----------
__global__ __launch_bounds__(256) void k_wavg(const float* __restrict__ act,
                                              const unsigned short* __restrict__ tp,
                                              float* __restrict__ partial) {
    const int kc = blockIdx.x;   // 32 chunks of 128 n
    const int b = blockIdx.y;    // 8
    const int d = threadIdx.x;
    const unsigned short* tpb = tp + ((size_t)b * N_ + kc * 128) * D_ + d;
    const float* actb = act + (size_t)b * O_ * N_ + kc * 128;
    float* pout = partial + ((size_t)(b * 32 + kc) * O_) * D_ + d;
    for (int oci = 0; oci < 2; ++oci) {
        const int oc = blockIdx.z * 2 + oci;
        float acc[10] = {};
        #pragma unroll 2
        for (int q = 0; q < 32; ++q) {
            float t0 = bf2f(tpb[(q * 4 + 0) * D_]);
            float t1 = bf2f(tpb[(q * 4 + 1) * D_]);
            float t2 = bf2f(tpb[(q * 4 + 2) * D_]);
            float t3 = bf2f(tpb[(q * 4 + 3) * D_]);
            #pragma unroll
            for (int oj = 0; oj < 10; ++oj) {
                float4 a4 = *(const float4*)(actb + (size_t)(oc * 10 + oj) * N_ + q * 4);
                acc[oj] += a4.x * t0 + a4.y * t1 + a4.z * t2 + a4.w * t3;
            }
        }
        #pragma unroll
        for (int oj = 0; oj < 10; ++oj)
            pout[(size_t)(oc * 10 + oj) * D_] = acc[oj];
    }
}

// ---------- gather + attention + Wv/Wo + LN + combine + final LN ----------
DEVI int swz(int j, int chunk) { return j * 512 + ((chunk ^ (j & 31)) << 4); }

__global__ __launch_bounds__(256) void k_attn(
    const unsigned short* __restrict__ tp, const int* __restrict__ oidx,
    const float* __restrict__ qW, const float* __restrict__ qbv,
    const float* __restrict__ Wv, const float* __restrict__ bv,
    const float* __restrict__ Wo, const float* __restrict__ bo,
    const float* __restrict__ g_pn, const float* __restrict__ bt_pn,
    const float* __restrict__ g_on, const float* __restrict__ bt_on,
    const float* __restrict__ partial, const float* __restrict__ asum,
    float* __restrict__ outp)
{
    __shared__ uint4 tgU[4096];      // 128 rows x 512B, chunk-XOR swizzle
    __shared__ float sc[H_ * K_];    // [h][j]; raw then normalized in place
    __shared__ float ul[H_ * D_];
    __shared__ float pool_lds[D_];
    __shared__ float redf[8];
    __shared__ int idxl[K_];
    char* tg = (char*)tgU;

    const int t = threadIdx.x, lane = t & 63, wid = t >> 6;
    const int blk = blockIdx.x;
    const int b = blk / O_;
    const int o = blk - b * O_;

    if (t < K_) idxl[t] = oidx[blk * K_ + t];
    __syncthreads();

    #pragma unroll
    for (int it = 0; it < 16; ++it) {      // gather top-128 token rows (bf16)
        int c = t + it * 256;
        int j = c >> 5, ch = c & 31;
        uint4 v = *(const uint4*)(tp + ((size_t)(b * N_ + idxl[j])) * D_ + ch * 8);
        *(uint4*)(tg + swz(j, ch)) = v;
    }
    __syncthreads();

    {   // QK: thread = (j = t&127, h-quad = t>>7): 4 scores per row pass
        const int j = t & 127, hq = t >> 7;
        const float* q0 = qW + hq * 4 * D_;
        float s0 = 0.f, s1 = 0.f, s2 = 0.f, s3 = 0.f;
        #pragma unroll 4
        for (int e8 = 0; e8 < 32; ++e8) {
            uint4 tv = *(const uint4*)(tg + swz(j, e8));
            float f0 = bf2f(tv.x & 0xffffu), f1 = bf2f(tv.x >> 16);
            float f2 = bf2f(tv.y & 0xffffu), f3 = bf2f(tv.y >> 16);
            float f4 = bf2f(tv.z & 0xffffu), f5 = bf2f(tv.z >> 16);
            float f6 = bf2f(tv.w & 0xffffu), f7 = bf2f(tv.w >> 16);
            const float* qa = q0 + e8 * 8;
            const float* qbp = qa + D_;
            const float* qc = qa + 2 * D_;
            const float* qd = qa + 3 * D_;
            s0 += f0*qa[0]+f1*qa[1]+f2*qa[2]+f3*qa[3]+f4*qa[4]+f5*qa[5]+f6*qa[6]+f7*qa[7];
            s1 += f0*qbp[0]+f1*qbp[1]+f2*qbp[2]+f3*qbp[3]+f4*qbp[4]+f5*qbp[5]+f6*qbp[6]+f7*qbp[7];
            s2 += f0*qc[0]+f1*qc[1]+f2*qc[2]+f3*qc[3]+f4*qc[4]+f5*qc[5]+f6*qc[6]+f7*qc[7];
            s3 += f0*qd[0]+f1*qd[1]+f2*qd[2]+f3*qd[3]+f4*qd[4]+f5*qd[5]+f6*qd[6]+f7*qd[7];
        }
        const float sca = 0.1767766952966369f;
        sc[(hq * 4 + 0) * K_ + j] = (s0 + qbv[hq * 4 + 0]) * sca;
        sc[(hq * 4 + 1) * K_ + j] = (s1 + qbv[hq * 4 + 1]) * sca;
        sc[(hq * 4 + 2) * K_ + j] = (s2 + qbv[hq * 4 + 2]) * sca;
        sc[(hq * 4 + 3) * K_ + j] = (s3 + qbv[hq * 4 + 3]) * sca;
    }
    __syncthreads();

    #pragma unroll
    for (int hh = 0; hh < 2; ++hh) {       // softmax per head, normalize in place
        int h = wid * 2 + hh;
        float v0 = sc[h * K_ + lane], v1 = sc[h * K_ + 64 + lane];
        float mx = fmaxf(v0, v1);
        #pragma unroll
        for (int m = 1; m < 64; m <<= 1) mx = fmaxf(mx, __shfl_xor(mx, m));
        float e0 = __expf(v0 - mx), e1 = __expf(v1 - mx);
        float ss = e0 + e1;
        #pragma unroll
        for (int m = 1; m < 64; m <<= 1) ss += __shfl_xor(ss, m);
        float inv = 1.0f / ss;
        sc[h * K_ + lane] = e0 * inv;
        sc[h * K_ + 64 + lane] = e1 * inv;
    }
    __syncthreads();

    {   // PV: thread = (h = t>>5, eg = t&31 -> 8 e's); b128 token reads + broadcast weights
        const int h = t >> 5, eg = t & 31;
        float a8[8] = {};
        #pragma unroll 2
        for (int jb = 0; jb < 32; ++jb) {
            f32x4 p4 = *(const f32x4*)(sc + h * K_ + jb * 4);
            #pragma unroll
            for (int ji = 0; ji < 4; ++ji) {
                int j = jb * 4 + ji;
                uint4 tv = *(const uint4*)(tg + swz(j, eg));
                float pw = p4[ji];
                a8[0] += pw * bf2f(tv.x & 0xffffu); a8[1] += pw * bf2f(tv.x >> 16);
                a8[2] += pw * bf2f(tv.y & 0xffffu); a8[3] += pw * bf2f(tv.y >> 16);
                a8[4] += pw * bf2f(tv.z & 0xffffu); a8[5] += pw * bf2f(tv.z >> 16);
                a8[6] += pw * bf2f(tv.w & 0xffffu); a8[7] += pw * bf2f(tv.w >> 16);
            }
        }
        #pragma unroll
        for (int i = 0; i < 8; ++i) ul[h * D_ + eg * 8 + i] = a8[i];
    }
    __syncthreads();

    {   // pooled[c] = u[h,:] @ Wv[:, c] + bv  (c = t, h = c>>5)
        int h = t >> 5;
        const float* up = ul + h * D_;
        float p = bv[t];
        #pragma unroll 8
        for (int e = 0; e < D_; ++e) p += up[e] * Wv[e * D_ + t];
        pool_lds[t] = p;
    }
    __syncthreads();
    float po = bo[t];
    #pragma unroll 8
    for (int e = 0; e < D_; ++e) po += pool_lds[e] * Wo[e * D_ + t];

    // LN (g_pn)
    float s1 = po, q1 = po * po;
    #pragma unroll
    for (int m = 1; m < 64; m <<= 1) { s1 += __shfl_xor(s1, m); q1 += __shfl_xor(q1, m); }
    if (!lane) { redf[wid] = s1; redf[4 + wid] = q1; }
    __syncthreads();
    s1 = redf[0] + redf[1] + redf[2] + redf[3];
    q1 = redf[4] + redf[5] + redf[6] + redf[7];
    float mean = s1 * (1.f/256.f);
    float var = q1 * (1.f/256.f) - mean * mean;
    float rs = rsqrtf(var + 1e-5f);
    float pl = (po - mean) * rs * g_pn[t] + bt_pn[t];
    __syncthreads();

    // combine with weighted average (sum 32 partials), final LN (g_on)
    float wa = 0.f;
    const float* pp = partial + ((size_t)(b * 32) * O_ + o) * D_ + t;
    #pragma unroll 8
    for (int kc = 0; kc < 32; ++kc) wa += pp[(size_t)kc * O_ * D_];
    float x = wa / asum[blk] + pl;
    float s2 = x, q2 = x * x;
    #pragma unroll
    for (int m = 1; m < 64; m <<= 1) { s2 += __shfl_xor(s2, m); q2 += __shfl_xor(q2, m); }
    if (!lane) { redf[wid] = s2; redf[4 + wid] = q2; }
    __syncthreads();
    s2 = redf[0] + redf[1] + redf[2] + redf[3];
    q2 = redf[4] + redf[5] + redf[6] + redf[7];
    float mean2 = s2 * (1.f/256.f);
    float var2 = q2 * (1.f/256.f) - mean2 * mean2;
    float rs2 = rsqrtf(var2 + 1e-5f);
    outp[(size_t)blk * D_ + t] = (x - mean2) * rs2 * g_on[t] + bt_on[t];
}

extern "C" void kernel_launch(void* const* d_in, const int* in_sizes, int n_in,
                              void* d_out, int out_size, void* d_ws, size_t ws_size,
                              hipStream_t stream) {
    const float* act    = (const float*)d_in[0];
    const float* tokens = (const float*)d_in[1];
    const float* W_tok  = (const float*)d_in[2];
    const float* b_tok  = (const float*)d_in[3];
    const float* g_tn   = (const float*)d_in[4];
    const float* bt_tn  = (const float*)d_in[5];
    const float* pq     = (const float*)d_in[6];
    const float* Wq     = (const float*)d_in[7];
    const float* bq     = (const float*)d_in[8];
    const float* Wk     = (const float*)d_in[9];
    const float* bk     = (const float*)d_in[10];
    const float* Wv     = (const float*)d_in[11];
    const float* bv     = (const float*)d_in[12];
    const float* Wo     = (const float*)d_in[13];
    const float* bo     = (const float*)d_in[14];
    const float* g_pn   = (const float*)d_in[15];
    const float* bt_pn  = (const float*)d_in[16];
    const float* g_on   = (const float*)d_in[17];
    const float* bt_on  = (const float*)d_in[18];

    char* ws = (char*)d_ws;
    unsigned short* wtb   = (unsigned short*)ws;                 // 1 MB
    unsigned short* tp    = (unsigned short*)(ws + 1048576);     // 16 MB
    int*   tidx = (int*)(ws + 17825792);                         // 409600
    float* asum = (float*)(ws + 18235392);                       // 3200
    float* part = (float*)(ws + 18238592);                       // 26.2 MB
    float* qW   = (float*)(ws + 44452992);                       // 8 KB
    float* qb   = (float*)(ws + 44461184);                       // 32 B

    k_pre<<<2856, 256, 0, stream>>>(act, tidx, asum, W_tok, wtb,
                                    pq, Wq, bq, Wk, bk, qW, qb);
    k_gemm1<<<M_ / 64, 512, 0, stream>>>(tokens, wtb, b_tok, g_tn, bt_tn, tp);
    k_wavg<<<dim3(32, 8, 5), 256, 0, stream>>>(act, tp, part);
    k_attn<<<B_ * O_, 256, 0, stream>>>(tp, tidx, qW, qb, Wv, bv, Wo, bo,
                                        g_pn, bt_pn, g_on, bt_on, part, asum,
                                        (float*)d_out);
}

// Round 12
// 220.178 us; speedup vs baseline: 1.7808x; 1.7808x over previous
//
#include <hip/hip_runtime.h>
#include <hip/hip_bf16.h>

#define DEVI static __device__ __forceinline__

typedef __attribute__((ext_vector_type(8))) short short8;
typedef __attribute__((ext_vector_type(4))) float f32x4;

#define B_   8
#define O_   100
#define N_   4096
#define TOKD 2048
#define D_   256
#define K_   128
#define H_   8
#define M_   (B_*N_)   // 32768

DEVI unsigned short f2bf(float f) {
    unsigned u = __float_as_uint(f);
    u = (u + 0x7FFFu + ((u >> 16) & 1u)) >> 16;   // RNE
    return (unsigned short)u;
}
DEVI float bf2f(unsigned v) { return __uint_as_float(v << 16); }

DEVI unsigned pkbf(float lo, float hi) {   // packed RNE f32->bf16 pair
    unsigned r;
    asm("v_cvt_pk_bf16_f32 %0, %1, %2" : "=v"(r) : "v"(lo), "v"(hi));
    return r;
}
DEVI void gload16(const void* g, void* l) {   // async global->LDS, 16B/lane
    __builtin_amdgcn_global_load_lds((const __attribute__((address_space(1))) void*)g,
                                     (__attribute__((address_space(3))) void*)l, 16, 0, 0);
}

// ---------- W_tok -> bf16^T, LDS-tiled: coalesced reads AND coalesced 512B writes ----------
__global__ __launch_bounds__(256) void k_trans(const float* __restrict__ W,
                                               unsigned short* __restrict__ wtb) {
    __shared__ unsigned short ldsT[32 * 264];   // [n][k] tile, padded stride
    const int t = threadIdx.x;
    const int k0 = (blockIdx.x >> 3) * 256;
    const int n0 = (blockIdx.x & 7) * 32;
    const int nn = t & 31, kk8 = t >> 5;        // lanes 0-31 contiguous n -> 128B runs
    #pragma unroll
    for (int r = 0; r < 32; ++r) {
        int k = r * 8 + kk8;
        ldsT[nn * 264 + k] = f2bf(W[(size_t)(k0 + k) * D_ + n0 + nn]);
    }
    __syncthreads();
    const int w = t >> 6, l = t & 63;
    #pragma unroll
    for (int rr = 0; rr < 8; ++rr) {            // one full 512B k-run per wave per rr
        int n = w * 8 + rr;
        ushort4 v = *(const ushort4*)(&ldsT[n * 264 + l * 4]);
        *(ushort4*)(wtb + (size_t)(n0 + n) * TOKD + k0 + l * 4) = v;
    }
}

// ---------- topk (blocks 0..799) + q-fold (800..807) ----------
__global__ __launch_bounds__(256) void k_topkqf(const float* __restrict__ act,
                                                int* __restrict__ oidx,
                                                float* __restrict__ asum,
                                                const float* __restrict__ pq,
                                                const float* __restrict__ Wq,
                                                const float* __restrict__ bqv,
                                                const float* __restrict__ Wk,
                                                const float* __restrict__ bkv,
                                                float* __restrict__ qW,
                                                float* __restrict__ qb) {
    __shared__ __align__(16) char smem[50304];
    const int t = threadIdx.x, lane = t & 63, wid = t >> 6;

    if (blockIdx.x >= 800) {
        // q-fold: qW[h][e] = qh[h]·Wk[e][h*32..], qb[h]
        float (*qpart)[32] = (float(*)[32])smem;
        float* qhl = (float*)(smem + 1024);
        const int h = blockIdx.x - 800;
        const int col = h * 32 + (t & 31), sl = t >> 5;
        float s = 0.f;
        #pragma unroll
        for (int e = 0; e < 32; ++e) s += pq[sl * 32 + e] * Wq[(sl * 32 + e) * D_ + col];
        qpart[sl][t & 31] = s;
        __syncthreads();
        if (t < 32) {
            float u = bqv[h * 32 + t];
            #pragma unroll
            for (int s8 = 0; s8 < 8; ++s8) u += qpart[s8][t];
            qhl[t] = u;
        }
        __syncthreads();
        float u = 0.f;
        #pragma unroll
        for (int dd = 0; dd < 32; ++dd) u += qhl[dd] * Wk[t * D_ + h * 32 + dd];
        qW[h * D_ + t] = u;
        if (t == 0) {
            float z = 0.f;
            for (int dd = 0; dd < 32; ++dd) z += qhl[dd] * bkv[h * 32 + dd];
            qb[h] = z;
        }
        return;
    }

    // ---- top-128 via value histogram (act uniform [0,1); exact jax tie-break at boundary)
    int* hist = (int*)smem;                               // 4096 bins
    unsigned long long* cand = (unsigned long long*)(smem + 16384);
    int* csum = (int*)(smem + 49152);
    int* sb   = (int*)(smem + 50192);
    int* cnts = (int*)(smem + 50200);
    float* redf = (float*)(smem + 50208);
    unsigned long long* redu = (unsigned long long*)(smem + 50224);

    const int blk = blockIdx.x;
    const float* rp = act + (size_t)blk * N_;
    float fv[16]; unsigned vb[16]; int bins[16];
    float fs = 0.f;
    #pragma unroll
    for (int i = 0; i < 16; ++i) {
        float f = rp[t + i * 256];
        fv[i] = f; vb[i] = __float_as_uint(f);
        fs += f;
    }
    #pragma unroll
    for (int i = 0; i < 16; ++i) hist[t + i * 256] = 0;
    if (t == 0) { cnts[0] = 0; cnts[1] = 0; }
    #pragma unroll
    for (int m = 1; m < 64; m <<= 1) fs += __shfl_xor(fs, m);
    if (!lane) redf[wid] = fs;
    __syncthreads();
    if (t == 0) asum[blk] = fmaxf(redf[0] + redf[1] + redf[2] + redf[3], 1e-8f);

    #pragma unroll
    for (int i = 0; i < 16; ++i) {
        float f = fv[i];
        int b = (f >= 1.0f) ? 4095 : ((f > 0.f) ? (int)(f * 4096.f) : 0);
        bins[i] = b;
        atomicAdd(&hist[b], 1);
    }
    __syncthreads();

    int cs = 0;
    #pragma unroll
    for (int i = 0; i < 16; ++i) cs += hist[t * 16 + i];
    int v = cs;
    #pragma unroll
    for (int off = 1; off < 64; off <<= 1) {
        int o = __shfl_down(v, off);
        if (lane + off < 64) v += o;
    }
    if (!lane) csum[256 + wid] = v;
    __syncthreads();
    int stot = 0;
    for (int w2 = wid + 1; w2 < 4; ++w2) stot += csum[256 + w2];
    int suff = v + stot;
    csum[t] = suff;
    __syncthreads();
    int nxtc = (t < 255) ? csum[t + 1] : 0;
    if (suff >= K_ && nxtc < K_) {
        int run = nxtc, bstar = t * 16;
        for (int bi = 15; bi >= 0; --bi) {
            run += hist[t * 16 + bi];
            if (run >= K_) { bstar = t * 16 + bi; break; }
        }
        sb[0] = bstar;
    }
    __syncthreads();
    const int bstar = sb[0];

    #pragma unroll
    for (int i = 0; i < 16; ++i) {
        if (bins[i] > bstar) {
            int p = atomicAdd(&cnts[0], 1);
            oidx[blk * K_ + p] = t + i * 256;
        } else if (bins[i] == bstar) {
            int p = atomicAdd(&cnts[1], 1);
            cand[p] = ((unsigned long long)vb[i] << 16) | (unsigned)(4095 - (t + i * 256));
        }
    }
    __syncthreads();
    const int g = cnts[0], E = cnts[1], m = K_ - g;
    unsigned long long last = ~0ull;
    for (int slot = 0; slot < m; ++slot) {
        unsigned long long best = 0;
        for (int i = t; i < E; i += 256) {
            unsigned long long e = cand[i];
            if (e < last && e > best) best = e;
        }
        #pragma unroll
        for (int mm = 1; mm < 64; mm <<= 1) {
            unsigned long long o = __shfl_xor(best, mm);
            if (o > best) best = o;
        }
        if (!lane) redu[wid] = best;
        __syncthreads();
        best = redu[0];
        if (redu[1] > best) best = redu[1];
        if (redu[2] > best) best = redu[2];
        if (redu[3] > best) best = redu[3];
        if (t == 0) oidx[blk * K_ + g + slot] = 4095 - (int)(best & 0xFFFFull);
        last = best;
        __syncthreads();
    }
}

// ---------- GEMM1 + bias + LN fused (R9 structure: 64x256 tile, BK=64, 80KB LDS, 2 blk/CU) ----------
__global__ __launch_bounds__(512, 2) void k_gemm1(const float* __restrict__ A,
                                                  const unsigned short* __restrict__ Bt,
                                                  const float* __restrict__ btok,
                                                  const float* __restrict__ g,
                                                  const float* __restrict__ bt,
                                                  unsigned short* __restrict__ tp) {
    __shared__ __align__(16) char smem[81920];
    const int t = threadIdx.x;
    const int bm = blockIdx.x;
    const int lane = t & 63, w = t >> 6;
    const int wm = w >> 2, wn = w & 3;       // 2x4 waves, wave tile 32x64
    const int lr = lane >> 4, lc = lane & 15;

    const int arow = t >> 3;
    const int acb = (t & 7) * 16;
    const float* agp = A + (size_t)(bm * 64 + arow) * TOKD + (t & 7) * 8;
    const int aw0 = arow * 128 + (acb ^ ((arow & 7) << 4));
    const unsigned short* bg = Bt + (size_t)(t >> 3) * TOKD
                        + (((((t & 7) << 4)) ^ (((t >> 3) & 7) << 4)) >> 1);
    char* bld = smem + 16384 + (w << 10);

    f32x4 acc[2][4] = {};
    const int NT = TOKD / 64;   // 32
    float4 a0, a1;

    a0 = *(const float4*)(agp); a1 = *(const float4*)(agp + 4);
    #pragma unroll
    for (int c = 0; c < 4; ++c) gload16(bg + (size_t)c * 64 * TOKD, bld + c * 8192);
    {
        uint4 v;
        v.x = pkbf(a0.x, a0.y); v.y = pkbf(a0.z, a0.w);
        v.z = pkbf(a1.x, a1.y); v.w = pkbf(a1.z, a1.w);
        *(uint4*)(smem + aw0) = v;
    }
    a0 = *(const float4*)(agp + 64); a1 = *(const float4*)(agp + 68);
    asm volatile("s_waitcnt vmcnt(2) lgkmcnt(0)" ::: "memory");
    __builtin_amdgcn_s_barrier();

    int cur = 0;
    for (int kt = 0; kt < NT; ++kt) {
        const int nxt = cur ^ 1;
        if (kt + 1 < NT) {
            const unsigned short* bn = bg + (size_t)(kt + 1) * 64;
            char* dst = bld + nxt * 32768;
            #pragma unroll
            for (int c = 0; c < 4; ++c) gload16(bn + (size_t)c * 64 * TOKD, dst + c * 8192);
        }
        const char* Ab = smem + cur * 8192;
        const char* Bb = smem + 16384 + cur * 32768;
        #pragma unroll
        for (int kk = 0; kk < 2; ++kk) {
            short8 afr[2], bfr[4];
            #pragma unroll
            for (int mi = 0; mi < 2; ++mi) {
                int row = wm * 32 + mi * 16 + lc;
                afr[mi] = *(const short8*)(Ab + row * 128 + ((kk * 64 + lr * 16) ^ ((row & 7) << 4)));
            }
            #pragma unroll
            for (int ni = 0; ni < 4; ++ni) {
                int n = wn * 64 + ni * 16 + lc;
                bfr[ni] = *(const short8*)(Bb + n * 128 + ((kk * 64 + lr * 16) ^ ((n & 7) << 4)));
            }
            __builtin_amdgcn_s_setprio(1);
            #pragma unroll
            for (int mi = 0; mi < 2; ++mi)
                #pragma unroll
                for (int ni = 0; ni < 4; ++ni)
                    acc[mi][ni] = __builtin_amdgcn_mfma_f32_16x16x32_bf16(afr[mi], bfr[ni], acc[mi][ni], 0, 0, 0);
            __builtin_amdgcn_s_setprio(0);
        }
        if (kt + 1 < NT) {
            uint4 v;
            v.x = pkbf(a0.x, a0.y); v.y = pkbf(a0.z, a0.w);
            v.z = pkbf(a1.x, a1.y); v.w = pkbf(a1.z, a1.w);
            *(uint4*)(smem + nxt * 8192 + aw0) = v;
            if (kt + 2 < NT) {
                const float* ap = agp + (size_t)(kt + 2) * 64;
                a0 = *(const float4*)(ap); a1 = *(const float4*)(ap + 4);
                asm volatile("s_waitcnt vmcnt(2) lgkmcnt(0)" ::: "memory");
            } else {
                asm volatile("s_waitcnt vmcnt(0) lgkmcnt(0)" ::: "memory");
            }
            __builtin_amdgcn_s_barrier();
            cur = nxt;
        }
    }
    __syncthreads();

    float* ep = (float*)smem;
    const int col0 = lane * 4;
    float4 b4 = *(const float4*)(btok + col0);
    float4 g4 = *(const float4*)(g + col0);
    float4 t4 = *(const float4*)(bt + col0);
    #pragma unroll
    for (int c = 0; c < 2; ++c) {
        if (wm == c) {
            #pragma unroll
            for (int mi = 0; mi < 2; ++mi)
                #pragma unroll
                for (int ni = 0; ni < 4; ++ni)
                    #pragma unroll
                    for (int r = 0; r < 4; ++r)
                        ep[(mi * 16 + lr * 4 + r) * 260 + wn * 64 + ni * 16 + lc] = acc[mi][ni][r];
        }
        __syncthreads();
        #pragma unroll
        for (int rr = 0; rr < 4; ++rr) {
            int row = w * 4 + rr;
            float4 x4 = *(const float4*)(ep + row * 260 + col0);
            float x0 = x4.x + b4.x, x1 = x4.y + b4.y, x2 = x4.z + b4.z, x3 = x4.w + b4.w;
            float s = x0 + x1 + x2 + x3;
            float q = x0*x0 + x1*x1 + x2*x2 + x3*x3;
            #pragma unroll
            for (int m = 1; m < 64; m <<= 1) { s += __shfl_xor(s, m); q += __shfl_xor(q, m); }
            float mean = s * (1.f/256.f);
            float var = q * (1.f/256.f) - mean * mean;
            float rs = rsqrtf(var + 1e-5f);
            ushort4 o;
            o.x = f2bf((x0-mean)*rs*g4.x + t4.x);
            o.y = f2bf((x1-mean)*rs*g4.y + t4.y);
            o.z = f2bf((x2-mean)*rs*g4.z + t4.z);
            o.w = f2bf((x3-mean)*rs*g4.w + t4.w);
            *(ushort4*)(tp + (size_t)(bm * 64 + c * 32 + row) * D_ + col0) = o;
        }
        __syncthreads();
    }
}

// ---------- weighted-average partials (grid z-split x5) ----------
__global__ __launch_bounds__(256) void k_wavg(const float* __restrict__ act,
                                              const unsigned short* __restrict__ tp,
                                              float* __restrict__ partial) {
    const int kc = blockIdx.x;
    const int b = blockIdx.y;
    const int d = threadIdx.x;
    const unsigned short* tpb = tp + ((size_t)b * N_ + kc * 128) * D_ + d;
    const float* actb = act + (size_t)b * O_ * N_ + kc * 128;
    float* pout = partial + ((size_t)(b * 32 + kc) * O_) * D_ + d;
    for (int oci = 0; oci < 2; ++oci) {
        const int oc = blockIdx.z * 2 + oci;
        float acc[10] = {};
        #pragma unroll 2
        for (int q = 0; q < 32; ++q) {
            float t0 = bf2f(tpb[(q * 4 + 0) * D_]);
            float t1 = bf2f(tpb[(q * 4 + 1) * D_]);
            float t2 = bf2f(tpb[(q * 4 + 2) * D_]);
            float t3 = bf2f(tpb[(q * 4 + 3) * D_]);
            #pragma unroll
            for (int oj = 0; oj < 10; ++oj) {
                float4 a4 = *(const float4*)(actb + (size_t)(oc * 10 + oj) * N_ + q * 4);
                acc[oj] += a4.x * t0 + a4.y * t1 + a4.z * t2 + a4.w * t3;
            }
        }
        #pragma unroll
        for (int oj = 0; oj < 10; ++oj)
            pout[(size_t)(oc * 10 + oj) * D_] = acc[oj];
    }
}

// ---------- attention v2: 2-pass tg (32KB), 37KB LDS -> 4 blocks/CU ----------
DEVI int swz64(int j, int chunk) { return j * 512 + ((chunk ^ (j & 31)) << 4); }

__global__ __launch_bounds__(256) void k_attn(
    const unsigned short* __restrict__ tp, const int* __restrict__ oidx,
    const float* __restrict__ qW, const float* __restrict__ qbv,
    const float* __restrict__ Wv, const float* __restrict__ bv,
    const float* __restrict__ Wo, const float* __restrict__ bo,
    const float* __restrict__ g_pn, const float* __restrict__ bt_pn,
    const float* __restrict__ g_on, const float* __restrict__ bt_on,
    const float* __restrict__ partial, const float* __restrict__ asum,
    float* __restrict__ outp)
{
    __shared__ __align__(16) char tg[32768];   // 64 rows x 512B, XOR-swizzled
    __shared__ float sc[H_ * K_];
    __shared__ float redf[8];
    __shared__ int idxl[K_];
    float* ul = (float*)tg;                    // alias: free after PV
    float* pool_lds = (float*)(tg + 8192);

    const int t = threadIdx.x, lane = t & 63, wid = t >> 6;
    const int blk = blockIdx.x;
    const int b = blk / O_;
    const int o = blk - b * O_;

    if (t < K_) idxl[t] = oidx[blk * K_ + t];
    __syncthreads();

    const int jq = t & 63, hp = t >> 6;        // QK: thread = (j, head-pair of wave)
    const float* qr0 = qW + (hp * 2) * D_;
    const float* qr1 = qr0 + D_;
    const float sca = 0.1767766952966369f;

    for (int pass = 0; pass < 2; ++pass) {
        #pragma unroll
        for (int it = 0; it < 8; ++it) {       // gather 64 rows
            int c = t + it * 256;
            int j = c >> 5, ch = c & 31;
            uint4 v = *(const uint4*)(tp + ((size_t)(b * N_ + idxl[pass * 64 + j])) * D_ + ch * 8);
            *(uint4*)(tg + swz64(j, ch)) = v;
        }
        __syncthreads();
        float s0 = 0.f, s1 = 0.f;
        #pragma unroll 4
        for (int e8 = 0; e8 < 32; ++e8) {
            uint4 tv = *(const uint4*)(tg + swz64(jq, e8));
            float f0 = bf2f(tv.x & 0xffffu), f1 = bf2f(tv.x >> 16);
            float f2 = bf2f(tv.y & 0xffffu), f3 = bf2f(tv.y >> 16);
            float f4 = bf2f(tv.z & 0xffffu), f5 = bf2f(tv.z >> 16);
            float f6 = bf2f(tv.w & 0xffffu), f7 = bf2f(tv.w >> 16);
            const float* qa = qr0 + e8 * 8;
            const float* qc = qr1 + e8 * 8;
            s0 += f0*qa[0]+f1*qa[1]+f2*qa[2]+f3*qa[3]+f4*qa[4]+f5*qa[5]+f6*qa[6]+f7*qa[7];
            s1 += f0*qc[0]+f1*qc[1]+f2*qc[2]+f3*qc[3]+f4*qc[4]+f5*qc[5]+f6*qc[6]+f7*qc[7];
        }
        sc[(hp * 2)     * K_ + pass * 64 + jq] = (s0 + qbv[hp * 2])     * sca;
        sc[(hp * 2 + 1) * K_ + pass * 64 + jq] = (s1 + qbv[hp * 2 + 1]) * sca;
        __syncthreads();
    }

    #pragma unroll
    for (int hh = 0; hh < 2; ++hh) {           // softmax per head
        int h = wid * 2 + hh;
        float v0 = sc[h * K_ + lane], v1 = sc[h * K_ + 64 + lane];
        float mx = fmaxf(v0, v1);
        #pragma unroll
        for (int m = 1; m < 64; m <<= 1) mx = fmaxf(mx, __shfl_xor(mx, m));
        float e0 = __expf(v0 - mx), e1 = __expf(v1 - mx);
        float ss = e0 + e1;
        #pragma unroll
        for (int m = 1; m < 64; m <<= 1) ss += __shfl_xor(ss, m);
        float inv = 1.0f / ss;
        sc[h * K_ + lane] = e0 * inv;
        sc[h * K_ + 64 + lane] = e1 * inv;
    }
    __syncthreads();

    // PV: pass 1 first (tg still holds rows 64..127), then re-gather rows 0..63
    const int hq5 = t >> 5, eg = t & 31;
    float a8[8] = {};
    #pragma unroll 2
    for (int jb = 0; jb < 16; ++jb) {
        f32x4 p4 = *(const f32x4*)(sc + hq5 * K_ + 64 + jb * 4);
        #pragma unroll
        for (int ji = 0; ji < 4; ++ji) {
            int j = jb * 4 + ji;
            uint4 tv = *(const uint4*)(tg + swz64(j, eg));
            float pw = p4[ji];
            a8[0] += pw * bf2f(tv.x & 0xffffu); a8[1] += pw * bf2f(tv.x >> 16);
            a8[2] += pw * bf2f(tv.y & 0xffffu); a8[3] += pw * bf2f(tv.y >> 16);
            a8[4] += pw * bf2f(tv.z & 0xffffu); a8[5] += pw * bf2f(tv.z >> 16);
            a8[6] += pw * bf2f(tv.w & 0xffffu); a8[7] += pw * bf2f(tv.w >> 16);
        }
    }
    __syncthreads();
    #pragma unroll
    for (int it = 0; it < 8; ++it) {           // re-gather rows 0..63
        int c = t + it * 256;
        int j = c >> 5, ch = c & 31;
        uint4 v = *(const uint4*)(tp + ((size_t)(b * N_ + idxl[j])) * D_ + ch * 8);
        *(uint4*)(tg + swz64(j, ch)) = v;
    }
    __syncthreads();
    #pragma unroll 2
    for (int jb = 0; jb < 16; ++jb) {
        f32x4 p4 = *(const f32x4*)(sc + hq5 * K_ + jb * 4);
        #pragma unroll
        for (int ji = 0; ji < 4; ++ji) {
            int j = jb * 4 + ji;
            uint4 tv = *(const uint4*)(tg + swz64(j, eg));
            float pw = p4[ji];
            a8[0] += pw * bf2f(tv.x & 0xffffu); a8[1] += pw * bf2f(tv.x >> 16);
            a8[2] += pw * bf2f(tv.y & 0xffffu); a8[3] += pw * bf2f(tv.y >> 16);
            a8[4] += pw * bf2f(tv.z & 0xffffu); a8[5] += pw * bf2f(tv.z >> 16);
            a8[6] += pw * bf2f(tv.w & 0xffffu); a8[7] += pw * bf2f(tv.w >> 16);
        }
    }
    __syncthreads();                            // tg reads done; safe to alias
    #pragma unroll
    for (int i = 0; i < 8; ++i) ul[hq5 * D_ + eg * 8 + i] = a8[i];
    __syncthreads();

    {   // pooled[c] = u[h,:] @ Wv[:, c] + bv, 4 independent accumulator chains
        int h = t >> 5;
        const float* up = ul + h * D_;
        float p0 = 0.f, p1 = 0.f, p2 = 0.f, p3 = 0.f;
        #pragma unroll 4
        for (int e = 0; e < 64; ++e) {
            p0 += up[e]       * Wv[(size_t)e         * D_ + t];
            p1 += up[e + 64]  * Wv[(size_t)(e + 64)  * D_ + t];
            p2 += up[e + 128] * Wv[(size_t)(e + 128) * D_ + t];
            p3 += up[e + 192] * Wv[(size_t)(e + 192) * D_ + t];
        }
        pool_lds[t] = bv[t] + ((p0 + p1) + (p2 + p3));
    }
    __syncthreads();
    float po;
    {
        float p0 = 0.f, p1 = 0.f, p2 = 0.f, p3 = 0.f;
        #pragma unroll 4
        for (int e = 0; e < 64; ++e) {
            p0 += pool_lds[e]       * Wo[(size_t)e         * D_ + t];
            p1 += pool_lds[e + 64]  * Wo[(size_t)(e + 64)  * D_ + t];
            p2 += pool_lds[e + 128] * Wo[(size_t)(e + 128) * D_ + t];
            p3 += pool_lds[e + 192] * Wo[(size_t)(e + 192) * D_ + t];
        }
        po = bo[t] + ((p0 + p1) + (p2 + p3));
    }

    // LN (g_pn)
    float lsm = po, lqm = po * po;
    #pragma unroll
    for (int m = 1; m < 64; m <<= 1) { lsm += __shfl_xor(lsm, m); lqm += __shfl_xor(lqm, m); }
    if (!lane) { redf[wid] = lsm; redf[4 + wid] = lqm; }
    __syncthreads();
    lsm = redf[0] + redf[1] + redf[2] + redf[3];
    lqm = redf[4] + redf[5] + redf[6] + redf[7];
    float mean = lsm * (1.f/256.f);
    float var = lqm * (1.f/256.f) - mean * mean;
    float rs = rsqrtf(var + 1e-5f);
    float pl = (po - mean) * rs * g_pn[t] + bt_pn[t];
    __syncthreads();

    // combine with weighted average (sum 32 partials), final LN (g_on)
    float wa = 0.f;
    const float* pp = partial + ((size_t)(b * 32) * O_ + o) * D_ + t;
    #pragma unroll 8
    for (int kc = 0; kc < 32; ++kc) wa += pp[(size_t)kc * O_ * D_];
    float x = wa / asum[blk] + pl;
    float s2 = x, q2 = x * x;
    #pragma unroll
    for (int m = 1; m < 64; m <<= 1) { s2 += __shfl_xor(s2, m); q2 += __shfl_xor(q2, m); }
    if (!lane) { redf[wid] = s2; redf[4 + wid] = q2; }
    __syncthreads();
    s2 = redf[0] + redf[1] + redf[2] + redf[3];
    q2 = redf[4] + redf[5] + redf[6] + redf[7];
    float mean2 = s2 * (1.f/256.f);
    float var2 = q2 * (1.f/256.f) - mean2 * mean2;
    float rs2 = rsqrtf(var2 + 1e-5f);
    outp[(size_t)blk * D_ + t] = (x - mean2) * rs2 * g_on[t] + bt_on[t];
}

extern "C" void kernel_launch(void* const* d_in, const int* in_sizes, int n_in,
                              void* d_out, int out_size, void* d_ws, size_t ws_size,
                              hipStream_t stream) {
    const float* act    = (const float*)d_in[0];
    const float* tokens = (const float*)d_in[1];
    const float* W_tok  = (const float*)d_in[2];
    const float* b_tok  = (const float*)d_in[3];
    const float* g_tn   = (const float*)d_in[4];
    const float* bt_tn  = (const float*)d_in[5];
    const float* pq     = (const float*)d_in[6];
    const float* Wq     = (const float*)d_in[7];
    const float* bq     = (const float*)d_in[8];
    const float* Wk     = (const float*)d_in[9];
    const float* bk     = (const float*)d_in[10];
    const float* Wv     = (const float*)d_in[11];
    const float* bv     = (const float*)d_in[12];
    const float* Wo     = (const float*)d_in[13];
    const float* bo     = (const float*)d_in[14];
    const float* g_pn   = (const float*)d_in[15];
    const float* bt_pn  = (const float*)d_in[16];
    const float* g_on   = (const float*)d_in[17];
    const float* bt_on  = (const float*)d_in[18];

    char* ws = (char*)d_ws;
    unsigned short* wtb   = (unsigned short*)ws;                 // 1 MB
    unsigned short* tp    = (unsigned short*)(ws + 1048576);     // 16 MB
    int*   tidx = (int*)(ws + 17825792);                         // 409600
    float* asum = (float*)(ws + 18235392);                       // 3200
    float* part = (float*)(ws + 18238592);                       // 26.2 MB
    float* qW   = (float*)(ws + 44452992);                       // 8 KB
    float* qb   = (float*)(ws + 44461184);                       // 32 B

    k_trans<<<64, 256, 0, stream>>>(W_tok, wtb);
    k_gemm1<<<M_ / 64, 512, 0, stream>>>(tokens, wtb, b_tok, g_tn, bt_tn, tp);
    k_wavg<<<dim3(32, 8, 5), 256, 0, stream>>>(act, tp, part);
    k_topkqf<<<808, 256, 0, stream>>>(act, tidx, asum, pq, Wq, bq, Wk, bk, qW, qb);
    k_attn<<<B_ * O_, 256, 0, stream>>>(tp, tidx, qW, qb, Wv, bv, Wo, bo,
                                        g_pn, bt_pn, g_on, bt_on, part, asum,
                                        (float*)d_out);
}